// Round 3
// baseline (68.461 us; speedup 1.0000x reference)
//
#include <hip/hip_runtime.h>

// Batched 10-qubit statevector sim, one wave64 per batch element.
// State: 1024 complex amps = 16 complex per lane (j = lane<<4 | r).
// Bit w of j == wire w. CNOT rings are folded away algebraically:
//   ring as GF(2) map b->Ab;  layer-2 RX on wire w becomes
//   psi'[j] = c*psi[j] - i*s*psi[j ^ d_w],  d_w = A^-1 e_w
//   measurement: z_i = sum_j |psi[j]|^2 * (-1)^popc(j & g_i), g_i = row i of A^2.

template<int DL, int DLN>
__device__ __forceinline__ void apply_gate(float (&ar)[16], float (&ai)[16],
                                           float c, float s) {
  float nr[16], ni[16];
#pragma unroll
  for (int r = 0; r < 16; ++r) {
    float pr, pi;
    if constexpr (DLN == 0) {
      pr = ar[r ^ DL];
      pi = ai[r ^ DL];
    } else {
      pr = __shfl_xor(ar[r ^ DL], DLN);
      pi = __shfl_xor(ai[r ^ DL], DLN);
    }
    // new = c*mine - i*s*partner  => re: c*ar + s*pi ; im: c*ai - s*pr
    nr[r] = fmaf(s, pi, c * ar[r]);
    ni[r] = fmaf(-s, pr, c * ai[r]);
  }
#pragma unroll
  for (int r = 0; r < 16; ++r) { ar[r] = nr[r]; ai[r] = ni[r]; }
}

__global__ void __launch_bounds__(256)
qsim_kernel(const float* __restrict__ x, const float* __restrict__ wts,
            float* __restrict__ out, int B) {
  const int lane = threadIdx.x & 63;
  const int b = blockIdx.x * 4 + (threadIdx.x >> 6);
  if (b >= B) return;

  // ---- per-wire 1q data: q_w = RX(th1_w) RY(x_w)|0>, and layer-2 cos/sin ----
  float qr0[10], qi0[10], qr1[10], qi1[10], c2[10], s2[10];
  const float* xb = x + b * 10;
#pragma unroll
  for (int w = 0; w < 10; ++w) {
    float xh = 0.5f * xb[w];
    float t1 = 0.5f * wts[w];
    float t2 = 0.5f * wts[10 + w];
    float cx = __cosf(xh), sx = __sinf(xh);
    float c1 = __cosf(t1), s1 = __sinf(t1);
    c2[w] = __cosf(t2);
    s2[w] = __sinf(t2);
    // RX(th1)*[cx,sx] = [c1*cx - i*s1*sx,  c1*sx - i*s1*cx]
    qr0[w] = c1 * cx;  qi0[w] = -s1 * sx;
    qr1[w] = c1 * sx;  qi1[w] = -s1 * cx;
  }

  // ---- lane prefix: product over wires 4..9 selected by lane bits ----
  float Pr = 1.0f, Pi = 0.0f;
#pragma unroll
  for (int w = 4; w < 10; ++w) {
    int bit = (lane >> (w - 4)) & 1;
    float qr = bit ? qr1[w] : qr0[w];
    float qi = bit ? qi1[w] : qi0[w];
    float nr = Pr * qr - Pi * qi;
    float ni = Pr * qi + Pi * qr;
    Pr = nr; Pi = ni;
  }

  // ---- local product over wires 0..3 (tensor doubling) ----
  float ar[16], ai[16];
  ar[0] = Pr; ai[0] = Pi;
#pragma unroll
  for (int w = 0; w < 4; ++w) {
#pragma unroll
    for (int r = 0; r < 8; ++r) {
      if (r < (1 << w)) {
        float lr = ar[r], li = ai[r];
        ar[r + (1 << w)] = lr * qr1[w] - li * qi1[w];
        ai[r + (1 << w)] = lr * qi1[w] + li * qr1[w];
        ar[r] = lr * qr0[w] - li * qi0[w];
        ai[r] = lr * qi0[w] + li * qr0[w];
      }
    }
  }

  // ---- layer-2 RX gates with relabeled XOR masks d_w ----
  // d: {0,1}=3 {1,2}=6 {2,3}=12 {3,4}=24 {4,5}=48 {5,6}=96 {6,7}=192
  //    {7,8}=384 {8,9}=768 {0,1,9}=515 ; template args <d&15, d>>4>
  apply_gate<3, 0>(ar, ai, c2[0], s2[0]);
  apply_gate<6, 0>(ar, ai, c2[1], s2[1]);
  apply_gate<12, 0>(ar, ai, c2[2], s2[2]);
  apply_gate<8, 1>(ar, ai, c2[3], s2[3]);
  apply_gate<0, 3>(ar, ai, c2[4], s2[4]);
  apply_gate<0, 6>(ar, ai, c2[5], s2[5]);
  apply_gate<0, 12>(ar, ai, c2[6], s2[6]);
  apply_gate<0, 24>(ar, ai, c2[7], s2[7]);
  apply_gate<0, 48>(ar, ai, c2[8], s2[8]);
  apply_gate<3, 32>(ar, ai, c2[9], s2[9]);

  // ---- probabilities + in-lane WHT over the 4 local bits ----
  float p[16];
#pragma unroll
  for (int r = 0; r < 16; ++r) p[r] = ar[r] * ar[r] + ai[r] * ai[r];
#pragma unroll
  for (int stp = 0; stp < 4; ++stp) {
    const int st = 1 << stp;
#pragma unroll
    for (int r = 0; r < 16; ++r) {
      if (!(r & st)) {
        float a0 = p[r], a1 = p[r | st];
        p[r] = a0 + a1;
        p[r | st] = a0 - a1;
      }
    }
  }

  // ---- z_i = Walsh coefficient at mask g_i = row i of A^2 ----
  constexpr int G[10] = {0x2AB, 0x3FD, 0x3FA, 0x3F5, 0x3EA,
                         0x3D5, 0x3AA, 0x355, 0x2AA, 0x155};
  float outv = 0.0f;
#pragma unroll
  for (int i = 0; i < 10; ++i) {
    float v = p[G[i] & 15];
    int par = __popc(lane & (G[i] >> 4)) & 1;
    v = par ? -v : v;
#pragma unroll
    for (int k = 1; k < 64; k <<= 1) v += __shfl_xor(v, k);
    if (lane == i) outv = v;
  }
  if (lane < 10) out[b * 10 + lane] = outv;
}

extern "C" void kernel_launch(void* const* d_in, const int* in_sizes, int n_in,
                              void* d_out, int out_size, void* d_ws, size_t ws_size,
                              hipStream_t stream) {
  const float* x = (const float*)d_in[0];
  const float* wts = (const float*)d_in[1];
  float* out = (float*)d_out;
  const int B = in_sizes[0] / 10;
  const int blocks = (B + 3) / 4;  // 4 waves (=4 batch elems) per 256-thread block
  qsim_kernel<<<blocks, 256, 0, stream>>>(x, wts, out, B);
}

// Round 4
// 62.711 us; speedup vs baseline: 1.0917x; 1.0917x over previous
//
#include <hip/hip_runtime.h>

// Batched 10-qubit statevector sim, one wave64 per batch element.
// State: 1024 complex amps = 16 complex per lane (j = lane<<4 | r).
// CNOT rings folded away over GF(2): layer-2 RX on wire w becomes
//   psi'[j] = c*psi[j] - i*s*psi[j ^ d_w],  d_w = A^-1 e_w
// Measurement: z_i = WHT of |psi|^2 at mask g_i = row i of A^2, extracted
// via full 64-lane WHT of the 4 needed in-register WHT outputs.

template<int CTRL>
__device__ __forceinline__ float dppf(float v) {
  int i = __builtin_bit_cast(int, v);
  i = __builtin_amdgcn_update_dpp(i, i, CTRL, 0xF, 0xF, false);
  return __builtin_bit_cast(float, i);
}
template<int PAT>
__device__ __forceinline__ float swzf(float v) {
  int i = __builtin_bit_cast(int, v);
  i = __builtin_amdgcn_ds_swizzle(i, PAT);
  return __builtin_bit_cast(float, i);
}

// partner fetch psi[. ^ (DLN<<4 | DL)]
template<int DL, int DLN>
__device__ __forceinline__ float fetchp(const float (&a)[16], int r) {
  float v = a[r ^ DL];
  if constexpr (DLN == 0)       return v;
  else if constexpr (DLN == 1)  return dppf<0xB1>(v);    // quad_perm xor1
  else if constexpr (DLN == 3)  return dppf<0x1B>(v);    // quad_perm xor3
  else if constexpr (DLN == 6)  return swzf<0x181F>(v);  // ds_swizzle xor6
  else if constexpr (DLN == 12) return swzf<0x301F>(v);  // xor12
  else if constexpr (DLN == 24) return swzf<0x601F>(v);  // xor24
  else                          return __shfl_xor(v, DLN); // 32, 48
}

template<int DL, int DLN>
__device__ __forceinline__ void apply_gate(float (&ar)[16], float (&ai)[16],
                                           float c, float s) {
  float nr[16], ni[16];
#pragma unroll
  for (int r = 0; r < 16; ++r) {
    float pr = fetchp<DL, DLN>(ar, r);
    float pi = fetchp<DL, DLN>(ai, r);
    // new = c*mine - i*s*partner  => re: c*ar + s*pi ; im: c*ai - s*pr
    nr[r] = fmaf(s, pi, c * ar[r]);
    ni[r] = fmaf(-s, pr, c * ai[r]);
  }
#pragma unroll
  for (int r = 0; r < 16; ++r) { ar[r] = nr[r]; ai[r] = ni[r]; }
}

// signed 64-lane WHT of one register: lane L ends with sum_L' (-1)^<L,L'> v_L'
__device__ __forceinline__ float lane_wht(float v, float g1, float g2, float g4,
                                          float g8, float g16, float g32) {
  v = fmaf(g1,  v, dppf<0xB1>(v));
  v = fmaf(g2,  v, dppf<0x4E>(v));     // quad_perm xor2
  v = fmaf(g4,  v, swzf<0x101F>(v));   // xor4
  v = fmaf(g8,  v, swzf<0x201F>(v));   // xor8
  v = fmaf(g16, v, swzf<0x401F>(v));   // xor16
  v = fmaf(g32, v, __shfl_xor(v, 32));
  return v;
}

__global__ void __launch_bounds__(256)
qsim_kernel(const float* __restrict__ x, const float* __restrict__ wts,
            float* __restrict__ out, int B) {
  const int lane = threadIdx.x & 63;
  const int b = blockIdx.x * 4 + (threadIdx.x >> 6);
  if (b >= B) return;
  const float* xb = x + b * 10;

  // ---- lane prefix: product over wires 4..9 selected by lane bits (on the fly)
  float Pr = 1.0f, Pi = 0.0f;
#pragma unroll
  for (int w = 4; w < 10; ++w) {
    float xh = 0.5f * xb[w];
    float t1 = 0.5f * wts[w];
    float cx = __cosf(xh), sx = __sinf(xh);
    float c1 = __cosf(t1), s1w = __sinf(t1);
    int bit = (lane >> (w - 4)) & 1;
    float qr = c1 * (bit ? sx : cx);
    float qi = -s1w * (bit ? cx : sx);
    float nr = Pr * qr - Pi * qi;
    float ni = Pr * qi + Pi * qr;
    Pr = nr; Pi = ni;
  }

  // ---- wires 0..3: q_w = RX(th1) RY(x)|0>, tensor doubling into registers
  float ar[16], ai[16];
  ar[0] = Pr; ai[0] = Pi;
#pragma unroll
  for (int w = 0; w < 4; ++w) {
    float xh = 0.5f * xb[w];
    float t1 = 0.5f * wts[w];
    float cx = __cosf(xh), sx = __sinf(xh);
    float c1 = __cosf(t1), s1w = __sinf(t1);
    float q0r = c1 * cx, q0i = -s1w * sx;
    float q1r = c1 * sx, q1i = -s1w * cx;
#pragma unroll
    for (int r = 0; r < 8; ++r) {
      if (r < (1 << w)) {
        float lr = ar[r], li = ai[r];
        ar[r + (1 << w)] = lr * q1r - li * q1i;
        ai[r + (1 << w)] = lr * q1i + li * q1r;
        ar[r] = lr * q0r - li * q0i;
        ai[r] = lr * q0i + li * q0r;
      }
    }
  }

  // ---- layer-2 cos/sin
  float c2[10], s2v[10];
#pragma unroll
  for (int w = 0; w < 10; ++w) {
    float t2 = 0.5f * wts[10 + w];
    c2[w] = __cosf(t2);
    s2v[w] = __sinf(t2);
  }

  // ---- layer-2 RX gates, XOR masks d_w (template <d&15, d>>4>)
  apply_gate<3, 0>(ar, ai, c2[0], s2v[0]);    // {0,1}
  apply_gate<6, 0>(ar, ai, c2[1], s2v[1]);    // {1,2}
  apply_gate<12, 0>(ar, ai, c2[2], s2v[2]);   // {2,3}
  apply_gate<8, 1>(ar, ai, c2[3], s2v[3]);    // {3,4}  DPP
  apply_gate<0, 3>(ar, ai, c2[4], s2v[4]);    // {4,5}  DPP
  apply_gate<0, 6>(ar, ai, c2[5], s2v[5]);    // {5,6}  swizzle
  apply_gate<0, 12>(ar, ai, c2[6], s2v[6]);   // {6,7}  swizzle
  apply_gate<0, 24>(ar, ai, c2[7], s2v[7]);   // {7,8}  swizzle
  apply_gate<0, 48>(ar, ai, c2[8], s2v[8]);   // {8,9}  shfl
  apply_gate<3, 32>(ar, ai, c2[9], s2v[9]);   // {0,1,9} shfl

  // ---- probabilities + exact in-lane WHT over the 4 register bits
  float p[16];
#pragma unroll
  for (int r = 0; r < 16; ++r) p[r] = ar[r] * ar[r] + ai[r] * ai[r];
#pragma unroll
  for (int stp = 0; stp < 4; ++stp) {
    const int st = 1 << stp;
#pragma unroll
    for (int r = 0; r < 16; ++r) {
      if (!(r & st)) {
        float a0 = p[r], a1 = p[r | st];
        p[r] = a0 + a1;
        p[r | st] = a0 - a1;
      }
    }
  }

  // ---- 64-lane WHT on the 4 needed registers; lane L = coeff at lane-mask L
  const float g1  = (lane & 1)  ? -1.0f : 1.0f;
  const float g2  = (lane & 2)  ? -1.0f : 1.0f;
  const float g4  = (lane & 4)  ? -1.0f : 1.0f;
  const float g8  = (lane & 8)  ? -1.0f : 1.0f;
  const float g16 = (lane & 16) ? -1.0f : 1.0f;
  const float g32 = (lane & 32) ? -1.0f : 1.0f;
  float w5  = lane_wht(p[5],  g1, g2, g4, g8, g16, g32);
  float w10 = lane_wht(p[10], g1, g2, g4, g8, g16, g32);
  float w11 = lane_wht(p[11], g1, g2, g4, g8, g16, g32);
  float w13 = lane_wht(p[13], g1, g2, g4, g8, g16, g32);

  // ---- z_i lives in lane (g_i>>4), register map below; g_i = row i of A^2
  // i : (reg, lane) = 0:(11,42) 1:(13,63) 2:(10,63) 3:(5,63) 4:(10,62)
  //                   5:(5,61) 6:(10,58) 7:(5,53) 8:(10,42) 9:(5,21)
  float* ob = out + b * 10;
  if (lane == 42) { ob[0] = w11; ob[8] = w10; }
  if (lane == 63) { ob[1] = w13; ob[2] = w10; ob[3] = w5; }
  if (lane == 62) { ob[4] = w10; }
  if (lane == 61) { ob[5] = w5; }
  if (lane == 58) { ob[6] = w10; }
  if (lane == 53) { ob[7] = w5; }
  if (lane == 21) { ob[9] = w5; }
}

extern "C" void kernel_launch(void* const* d_in, const int* in_sizes, int n_in,
                              void* d_out, int out_size, void* d_ws, size_t ws_size,
                              hipStream_t stream) {
  const float* x = (const float*)d_in[0];
  const float* wts = (const float*)d_in[1];
  float* out = (float*)d_out;
  const int B = in_sizes[0] / 10;
  const int blocks = (B + 3) / 4;  // 4 waves (=4 batch elems) per 256-thread block
  qsim_kernel<<<blocks, 256, 0, stream>>>(x, wts, out, B);
}

// Round 8
// 62.171 us; speedup vs baseline: 1.1012x; 1.0087x over previous
//
#include <hip/hip_runtime.h>

// Batched 10-qubit statevector sim, one wave64 per batch element.
// State: 1024 complex amps = 16 complex per lane (j = lane<<4 | r).
// CNOT rings folded away over GF(2): layer-2 RX on wire w becomes
//   psi'[j] = c*psi[j] - i*s*psi[j ^ d_w],  d_w = A^-1 e_w
// Measurement: z_i = WHT of |psi|^2 at mask g_i = row i of A^2.
// Cross-lane primitives: round-4-verified ds_swizzle/shfl/quad_perm only,
// plus ONE new candidate under bisect: DPP row_ror:8 for lane^8
// (rotation by 8 in a 16-ring = xor8 regardless of rotate direction).
// permlane16/32_swap sum-trick REMOVED — prime suspect for round-5's
// absmax=2.96 failure.

template<int CTRL>
__device__ __forceinline__ float dppf(float v) {
  int i = __builtin_bit_cast(int, v);
  i = __builtin_amdgcn_update_dpp(i, i, CTRL, 0xF, 0xF, false);
  return __builtin_bit_cast(float, i);
}
template<int PAT>
__device__ __forceinline__ float swzf(float v) {
  int i = __builtin_bit_cast(int, v);
  i = __builtin_amdgcn_ds_swizzle(i, PAT);
  return __builtin_bit_cast(float, i);
}

// partner fetch psi[. ^ (DLN<<4 | DL)]
template<int DL, int DLN>
__device__ __forceinline__ float fetchp(const float (&a)[16], int r) {
  float v = a[r ^ DL];
  if constexpr (DLN == 0)       return v;
  else if constexpr (DLN == 1)  return dppf<0xB1>(v);    // quad_perm xor1
  else if constexpr (DLN == 3)  return dppf<0x1B>(v);    // quad_perm xor3
  else if constexpr (DLN == 6)  return swzf<0x181F>(v);  // ds_swizzle xor6
  else if constexpr (DLN == 12) return swzf<0x301F>(v);  // xor12
  else if constexpr (DLN == 24) return swzf<0x601F>(v);  // xor24
  else                          return __shfl_xor(v, DLN); // 32, 48
}

template<int DL, int DLN>
__device__ __forceinline__ void apply_gate(float (&ar)[16], float (&ai)[16],
                                           float c, float s) {
  float nr[16], ni[16];
#pragma unroll
  for (int r = 0; r < 16; ++r) {
    float pr = fetchp<DL, DLN>(ar, r);
    float pi = fetchp<DL, DLN>(ai, r);
    // new = c*mine - i*s*partner  => re: c*ar + s*pi ; im: c*ai - s*pr
    nr[r] = fmaf(s, pi, c * ar[r]);
    ni[r] = fmaf(-s, pr, c * ai[r]);
  }
#pragma unroll
  for (int r = 0; r < 16; ++r) { ar[r] = nr[r]; ai[r] = ni[r]; }
}

// signed 64-lane WHT of one register: lane L ends with sum_L' (-1)^<L,L'> v_L'
__device__ __forceinline__ float lane_wht(float v, float g1, float g2, float g4,
                                          float g8, float g16, float g32) {
  v = fmaf(g1,  v, dppf<0xB1>(v));    // xor1  quad_perm   (verified r4)
  v = fmaf(g2,  v, dppf<0x4E>(v));    // xor2  quad_perm   (verified r4)
  v = fmaf(g4,  v, swzf<0x101F>(v));  // xor4  swizzle     (verified r4)
  v = fmaf(g8,  v, dppf<0x128>(v));   // xor8  row_ror:8   <-- BISECT CANDIDATE
  v = fmaf(g16, v, swzf<0x401F>(v));  // xor16 swizzle     (verified r4)
  v = fmaf(g32, v, __shfl_xor(v, 32));// xor32 shfl        (verified r4)
  return v;
}

__global__ void __launch_bounds__(256)
qsim_kernel(const float* __restrict__ x, const float* __restrict__ wts,
            float* __restrict__ out, int B) {
  const int lane = threadIdx.x & 63;
  const int b = blockIdx.x * 4 + (threadIdx.x >> 6);
  if (b >= B) return;
  const float* xb = x + b * 10;

  // ---- lane prefix: product over wires 4..9 selected by lane bits (on the fly)
  float Pr = 1.0f, Pi = 0.0f;
#pragma unroll
  for (int w = 4; w < 10; ++w) {
    float xh = 0.5f * xb[w];
    float t1 = 0.5f * wts[w];
    float cx = __cosf(xh), sx = __sinf(xh);
    float c1 = __cosf(t1), s1w = __sinf(t1);
    int bit = (lane >> (w - 4)) & 1;
    float qr = c1 * (bit ? sx : cx);
    float qi = -s1w * (bit ? cx : sx);
    float nr = Pr * qr - Pi * qi;
    float ni = Pr * qi + Pi * qr;
    Pr = nr; Pi = ni;
  }

  // ---- wires 0..3: q_w = RX(th1) RY(x)|0>, tensor doubling into registers
  float ar[16], ai[16];
  ar[0] = Pr; ai[0] = Pi;
#pragma unroll
  for (int w = 0; w < 4; ++w) {
    float xh = 0.5f * xb[w];
    float t1 = 0.5f * wts[w];
    float cx = __cosf(xh), sx = __sinf(xh);
    float c1 = __cosf(t1), s1w = __sinf(t1);
    float q0r = c1 * cx, q0i = -s1w * sx;
    float q1r = c1 * sx, q1i = -s1w * cx;
#pragma unroll
    for (int r = 0; r < 8; ++r) {
      if (r < (1 << w)) {
        float lr = ar[r], li = ai[r];
        ar[r + (1 << w)] = lr * q1r - li * q1i;
        ai[r + (1 << w)] = lr * q1i + li * q1r;
        ar[r] = lr * q0r - li * q0i;
        ai[r] = lr * q0i + li * q0r;
      }
    }
  }

  // ---- layer-2 cos/sin
  float c2[10], s2v[10];
#pragma unroll
  for (int w = 0; w < 10; ++w) {
    float t2 = 0.5f * wts[10 + w];
    c2[w] = __cosf(t2);
    s2v[w] = __sinf(t2);
  }

  // ---- layer-2 RX gates, XOR masks d_w (template <d&15, d>>4>)
  apply_gate<3, 0>(ar, ai, c2[0], s2v[0]);    // {0,1}   reg-only
  apply_gate<6, 0>(ar, ai, c2[1], s2v[1]);    // {1,2}   reg-only
  apply_gate<12, 0>(ar, ai, c2[2], s2v[2]);   // {2,3}   reg-only
  apply_gate<8, 1>(ar, ai, c2[3], s2v[3]);    // {3,4}   DPP quad
  apply_gate<0, 3>(ar, ai, c2[4], s2v[4]);    // {4,5}   DPP quad
  apply_gate<0, 6>(ar, ai, c2[5], s2v[5]);    // {5,6}   swizzle
  apply_gate<0, 12>(ar, ai, c2[6], s2v[6]);   // {6,7}   swizzle
  apply_gate<0, 24>(ar, ai, c2[7], s2v[7]);   // {7,8}   swizzle
  apply_gate<0, 48>(ar, ai, c2[8], s2v[8]);   // {8,9}   shfl
  apply_gate<3, 32>(ar, ai, c2[9], s2v[9]);   // {0,1,9} shfl

  // ---- probabilities + exact in-lane WHT over the 4 register bits
  float p[16];
#pragma unroll
  for (int r = 0; r < 16; ++r) p[r] = ar[r] * ar[r] + ai[r] * ai[r];
#pragma unroll
  for (int stp = 0; stp < 4; ++stp) {
    const int st = 1 << stp;
#pragma unroll
    for (int r = 0; r < 16; ++r) {
      if (!(r & st)) {
        float a0 = p[r], a1 = p[r | st];
        p[r] = a0 + a1;
        p[r | st] = a0 - a1;
      }
    }
  }

  // ---- 64-lane WHT on the 4 needed registers; lane L = coeff at lane-mask L
  const float g1  = (lane & 1)  ? -1.0f : 1.0f;
  const float g2  = (lane & 2)  ? -1.0f : 1.0f;
  const float g4  = (lane & 4)  ? -1.0f : 1.0f;
  const float g8  = (lane & 8)  ? -1.0f : 1.0f;
  const float g16 = (lane & 16) ? -1.0f : 1.0f;
  const float g32 = (lane & 32) ? -1.0f : 1.0f;
  float w5  = lane_wht(p[5],  g1, g2, g4, g8, g16, g32);
  float w10 = lane_wht(p[10], g1, g2, g4, g8, g16, g32);
  float w11 = lane_wht(p[11], g1, g2, g4, g8, g16, g32);
  float w13 = lane_wht(p[13], g1, g2, g4, g8, g16, g32);

  // ---- z_i lives in lane (g_i>>4), register map below; g_i = row i of A^2
  // i : (reg, lane) = 0:(11,42) 1:(13,63) 2:(10,63) 3:(5,63) 4:(10,62)
  //                   5:(5,61) 6:(10,58) 7:(5,53) 8:(10,42) 9:(5,21)
  float* ob = out + b * 10;
  if (lane == 42) { ob[0] = w11; ob[8] = w10; }
  if (lane == 63) { ob[1] = w13; ob[2] = w10; ob[3] = w5; }
  if (lane == 62) { ob[4] = w10; }
  if (lane == 61) { ob[5] = w5; }
  if (lane == 58) { ob[6] = w10; }
  if (lane == 53) { ob[7] = w5; }
  if (lane == 21) { ob[9] = w5; }
}

extern "C" void kernel_launch(void* const* d_in, const int* in_sizes, int n_in,
                              void* d_out, int out_size, void* d_ws, size_t ws_size,
                              hipStream_t stream) {
  const float* x = (const float*)d_in[0];
  const float* wts = (const float*)d_in[1];
  float* out = (float*)d_out;
  const int B = in_sizes[0] / 10;
  const int blocks = (B + 3) / 4;  // 4 waves (=4 batch elems) per 256-thread block
  qsim_kernel<<<blocks, 256, 0, stream>>>(x, wts, out, B);
}